// Round 11
// baseline (169.928 us; speedup 1.0000x reference)
//
#include <hip/hip_runtime.h>
#include <hip/hip_bf16.h>

#define D 64
#define CAP 32      // slots per node = one 64B line; overflow -> side list
#define EUNROLL 4
#define OVF_CAP 16384

__device__ __forceinline__ float bf2f(unsigned short u) {
    return __uint_as_float((unsigned int)u << 16);
}
__device__ __forceinline__ unsigned short f2bf(float f) {
    unsigned int u = __float_as_uint(f);
    unsigned int r = (u + 0x7fffu + ((u >> 16) & 1u)) >> 16;   // RNE
    return (unsigned short)r;
}

// ---------- Kernel 1: m planes = bf16(relu(x @ W + b)); zero cnt + ovf_cnt ----------
// m stored as two half-planes: m0 = cols 0..31, m1 = cols 32..63 (3.2 MB each,
// so each gather pass's working set fits a 4 MiB per-XCD L2).
__global__ __launch_bounds__(256) void node_mlp_kernel(
    const float* __restrict__ x, const float* __restrict__ W,
    const float* __restrict__ b, unsigned short* __restrict__ m0,
    unsigned short* __restrict__ m1, int* __restrict__ cnt,
    int* __restrict__ ovf_cnt, int n_nodes) {
    for (int i = blockIdx.x * blockDim.x + threadIdx.x; i < n_nodes;
         i += gridDim.x * blockDim.x) cnt[i] = 0;
    if (blockIdx.x == 0 && threadIdx.x == 0) *ovf_cnt = 0;

    const int lane = threadIdx.x & 63;
    const int l31 = lane & 31;
    unsigned short* mp = (lane < 32) ? m0 : m1;
    float w[D];
    #pragma unroll
    for (int k = 0; k < D; ++k) w[k] = W[k * D + lane];
    const float bias = b[lane];

    const int wave = (blockIdx.x * blockDim.x + threadIdx.x) >> 6;
    const int nwaves = (gridDim.x * blockDim.x) >> 6;

    for (int row = wave; row < n_nodes; row += nwaves) {
        const float4* xr = (const float4*)(x + (size_t)row * D);
        float acc = bias;
        #pragma unroll
        for (int kk = 0; kk < D / 4; ++kk) {
            float4 xv = xr[kk];   // wave-uniform address -> broadcast, 1 request
            acc = fmaf(xv.x, w[4 * kk + 0], acc);
            acc = fmaf(xv.y, w[4 * kk + 1], acc);
            acc = fmaf(xv.z, w[4 * kk + 2], acc);
            acc = fmaf(xv.w, w[4 * kk + 3], acc);
        }
        mp[(size_t)row * 32 + l31] = f2bf(fmaxf(acc, 0.0f));
    }
}

// ---------- Kernel 2: append src into per-dst slot rows (1 line/row), ovf side list ----------
__global__ __launch_bounds__(256) void append_kernel(
    const int* __restrict__ src, const int* __restrict__ dst,
    int* __restrict__ cnt, unsigned short* __restrict__ slots,
    int* __restrict__ ovf_cnt, unsigned int* __restrict__ ovf, int n_edges) {
    const int base = blockIdx.x * 256 * EUNROLL + threadIdx.x;
    int s[EUNROLL], d[EUNROLL], pos[EUNROLL];
    bool ok[EUNROLL];
    #pragma unroll
    for (int i = 0; i < EUNROLL; ++i) {            // coalesced loads
        int e = base + i * 256;
        ok[i] = (e < n_edges);
        s[i] = ok[i] ? src[e] : 0;
        d[i] = ok[i] ? dst[e] : 0;
    }
    #pragma unroll
    for (int i = 0; i < EUNROLL; ++i)              // independent atomics in flight
        pos[i] = ok[i] ? atomicAdd(&cnt[d[i]], 1) : CAP;
    #pragma unroll
    for (int i = 0; i < EUNROLL; ++i) {
        if (!ok[i]) continue;
        if (pos[i] < CAP) {
            slots[(size_t)d[i] * CAP + pos[i]] = (unsigned short)s[i];
        } else {                                    // ~4 nodes expected (P~8e-5)
            int op = atomicAdd(ovf_cnt, 1);
            if (op < OVF_CAP)
                ovf[op] = ((unsigned int)d[i] << 16) | (unsigned int)s[i];
        }
    }
}

// ---------- Kernel 3 (x2): gather one 32-col half-plane; 2 nodes per wave ----------
// mplane is 3.2 MB -> L2-resident per XCD. Overflow handled by the owning
// half-wave (scan tiny list) so the plain out-store stays race-free.
__global__ __launch_bounds__(256) void gather_pass_kernel(
    const unsigned short* __restrict__ slots, const int* __restrict__ cnt,
    const unsigned short* __restrict__ mplane,
    const int* __restrict__ ovf_cnt, const unsigned int* __restrict__ ovf,
    float* __restrict__ out, int n_nodes, int col0) {
    const int lane = threadIdx.x & 63;
    const int l31 = lane & 31;
    const int wave = (blockIdx.x * 256 + threadIdx.x) >> 6;
    const int node = wave * 2 + ((lane >> 5) & 1);
    if (node >= n_nodes) return;

    const int c = cnt[node];
    const int cc = min(c, CAP);
    unsigned int idx = (unsigned int)slots[(size_t)node * CAP + l31];
    const int bsel = lane & 32;   // broadcast source base for this half-wave

    float acc = 0.0f;
    int k = 0;
    for (; k + 4 <= cc; k += 4) {
        unsigned int s0 = __shfl(idx, bsel + k + 0);
        unsigned int s1 = __shfl(idx, bsel + k + 1);
        unsigned int s2 = __shfl(idx, bsel + k + 2);
        unsigned int s3 = __shfl(idx, bsel + k + 3);
        float v0 = bf2f(mplane[(size_t)s0 * 32 + l31]);  // 64B row, L2-hot
        float v1 = bf2f(mplane[(size_t)s1 * 32 + l31]);
        float v2 = bf2f(mplane[(size_t)s2 * 32 + l31]);
        float v3 = bf2f(mplane[(size_t)s3 * 32 + l31]);
        acc += (v0 + v1) + (v2 + v3);
    }
    for (; k < cc; ++k) {
        unsigned int s = __shfl(idx, bsel + k);
        acc += bf2f(mplane[(size_t)s * 32 + l31]);
    }
    if (c > CAP) {                                   // rare: scan the tiny ovf list
        int oc = min(*ovf_cnt, OVF_CAP);
        for (int i = 0; i < oc; ++i) {
            unsigned int e = ovf[i];
            if ((int)(e >> 16) == node)
                acc += bf2f(mplane[(size_t)(e & 0xFFFFu) * 32 + l31]);
        }
    }
    out[(size_t)node * D + col0 + l31] = acc;
}

// ---------- Fallback: atomic scatter (plane layout) ----------
__global__ __launch_bounds__(256) void edge_scatter_kernel(
    const int* __restrict__ src, const int* __restrict__ dst,
    const unsigned short* __restrict__ m0, const unsigned short* __restrict__ m1,
    float* __restrict__ out, int n_edges) {
    long long t = (long long)blockIdx.x * blockDim.x + threadIdx.x;
    int e = (int)(t >> 4);
    if (e >= n_edges) return;
    int c = (int)(t & 15) << 2;
    int s = src[e];
    int d = dst[e];
    const unsigned short* mp = (c < 32) ? m0 : m1;
    const ushort4 v = *(const ushort4*)(mp + (size_t)s * 32 + (c & 31));
    float* o = out + (size_t)d * D + c;
    atomicAdd(o + 0, bf2f(v.x));
    atomicAdd(o + 1, bf2f(v.y));
    atomicAdd(o + 2, bf2f(v.z));
    atomicAdd(o + 3, bf2f(v.w));
}

static inline size_t align_up(size_t v, size_t a) { return (v + a - 1) & ~(a - 1); }

extern "C" void kernel_launch(void* const* d_in, const int* in_sizes, int n_in,
                              void* d_out, int out_size, void* d_ws, size_t ws_size,
                              hipStream_t stream) {
    const float* x = (const float*)d_in[0];
    const int* edge_index = (const int*)d_in[1];   // int32 per harness contract
    const float* W = (const float*)d_in[2];
    const float* b = (const float*)d_in[3];
    float* out = (float*)d_out;

    const int n_nodes = in_sizes[0] / D;        // 50000
    const int n_edges = in_sizes[1] / 2;        // 800000
    const int* src = edge_index;                // row 0 (j, gather)
    const int* dst = edge_index + n_edges;      // row 1 (i, scatter)

    // Workspace layout (~10 MB total)
    size_t off = 0;
    unsigned short* m0 = (unsigned short*)((char*)d_ws + off);
    off = align_up(off + (size_t)n_nodes * 32 * sizeof(unsigned short), 256);
    unsigned short* m1 = (unsigned short*)((char*)d_ws + off);
    off = align_up(off + (size_t)n_nodes * 32 * sizeof(unsigned short), 256);
    int* cnt = (int*)((char*)d_ws + off);
    off = align_up(off + (size_t)n_nodes * sizeof(int), 256);
    unsigned short* slots = (unsigned short*)((char*)d_ws + off);
    off = align_up(off + (size_t)n_nodes * CAP * sizeof(unsigned short), 256);
    int* ovf_cnt = (int*)((char*)d_ws + off);
    off = align_up(off + sizeof(int), 256);
    unsigned int* ovf = (unsigned int*)((char*)d_ws + off);
    off = align_up(off + (size_t)OVF_CAP * sizeof(unsigned int), 256);
    const size_t needed = off;

    // Node MLP (+ fused cnt/ovf zeroing): 512 blocks -> 8 waves/CU
    node_mlp_kernel<<<512, 256, 0, stream>>>(x, W, b, m0, m1, cnt, ovf_cnt, n_nodes);

    if (ws_size >= needed && n_nodes <= 65536) {
        const int ablocks = (n_edges + 256 * EUNROLL - 1) / (256 * EUNROLL);
        append_kernel<<<ablocks, 256, 0, stream>>>(src, dst, cnt, slots,
                                                   ovf_cnt, ovf, n_edges);
        const int gblocks = (n_nodes + 7) / 8;   // 8 nodes per 256-thread block
        gather_pass_kernel<<<gblocks, 256, 0, stream>>>(
            slots, cnt, m0, ovf_cnt, ovf, out, n_nodes, 0);
        gather_pass_kernel<<<gblocks, 256, 0, stream>>>(
            slots, cnt, m1, ovf_cnt, ovf, out, n_nodes, 32);
    } else {
        hipMemsetAsync(d_out, 0, (size_t)out_size * sizeof(float), stream);
        long long total_threads = (long long)n_edges * 16;
        int scat_blocks = (int)((total_threads + 255) / 256);
        edge_scatter_kernel<<<scat_blocks, 256, 0, stream>>>(src, dst, m0, m1,
                                                             out, n_edges);
    }
}

// Round 12
// 158.343 us; speedup vs baseline: 1.0732x; 1.0732x over previous
//
#include <hip/hip_runtime.h>
#include <hip/hip_bf16.h>

#define D 64
#define CAP 32      // slots per node = one 64B line (row == line)
#define OVF_CAP 16384
#define NSHARD 8    // dst shards, bound to XCDs via blockIdx&7 heuristic

__device__ __forceinline__ float bf2f(unsigned short u) {
    return __uint_as_float((unsigned int)u << 16);
}
__device__ __forceinline__ unsigned short f2bf(float f) {
    unsigned int u = __float_as_uint(f);
    unsigned int r = (u + 0x7fffu + ((u >> 16) & 1u)) >> 16;   // RNE
    return (unsigned short)r;
}

// ---------- Kernel 1: m planes = bf16(relu(x @ W + b)); zero cnt + ovf_cnt ----------
// m as two half-planes (3.2 MB each -> per-XCD-L2-resident during gather).
__global__ __launch_bounds__(256) void node_mlp_kernel(
    const float* __restrict__ x, const float* __restrict__ W,
    const float* __restrict__ b, unsigned short* __restrict__ m0,
    unsigned short* __restrict__ m1, int* __restrict__ cnt,
    int* __restrict__ ovf_cnt, int n_nodes) {
    for (int i = blockIdx.x * blockDim.x + threadIdx.x; i < n_nodes;
         i += gridDim.x * blockDim.x) cnt[i] = 0;
    if (blockIdx.x == 0 && threadIdx.x == 0) *ovf_cnt = 0;

    const int lane = threadIdx.x & 63;
    const int l31 = lane & 31;
    unsigned short* mp = (lane < 32) ? m0 : m1;
    float w[D];
    #pragma unroll
    for (int k = 0; k < D; ++k) w[k] = W[k * D + lane];
    const float bias = b[lane];

    const int wave = (blockIdx.x * blockDim.x + threadIdx.x) >> 6;
    const int nwaves = (gridDim.x * blockDim.x) >> 6;

    for (int row = wave; row < n_nodes; row += nwaves) {
        const float4* xr = (const float4*)(x + (size_t)row * D);
        float acc = bias;
        #pragma unroll
        for (int kk = 0; kk < D / 4; ++kk) {
            float4 xv = xr[kk];   // wave-uniform address -> broadcast, 1 request
            acc = fmaf(xv.x, w[4 * kk + 0], acc);
            acc = fmaf(xv.y, w[4 * kk + 1], acc);
            acc = fmaf(xv.z, w[4 * kk + 2], acc);
            acc = fmaf(xv.w, w[4 * kk + 3], acc);
        }
        mp[(size_t)row * 32 + l31] = f2bf(fmaxf(acc, 0.0f));
    }
}

// ---------- Kernel 2: XCD-sharded append ----------
// Block group k (blockIdx&7==k, co-resident on one XCD under round-robin
// dispatch) handles only dst with (d&7)==k, so each slot line is written by
// one XCD and L2 merges the ~16 stores into a single writeback.
// Correctness does NOT depend on the XCD mapping — sharding is by blockIdx.
__global__ __launch_bounds__(256) void append_kernel(
    const int* __restrict__ src, const int* __restrict__ dst,
    int* __restrict__ cnt, unsigned short* __restrict__ slots,
    int* __restrict__ ovf_cnt, unsigned int* __restrict__ ovf,
    int n_edges, int blocks_per_shard) {
    const int shard = blockIdx.x & (NSHARD - 1);
    const int p = blockIdx.x >> 3;          // rank within shard group
    const int chunk = (n_edges + blocks_per_shard - 1) / blocks_per_shard;
    const int beg = p * chunk;
    const int end = min(beg + chunk, n_edges);

    for (int e = beg + (int)threadIdx.x; e < end; e += 256) {
        int d = dst[e];                      // coalesced; L3-served (8x redundant)
        if ((d & (NSHARD - 1)) != shard) continue;
        int s = src[e];
        int pos = atomicAdd(&cnt[d], 1);     // memory-side atomic
        if (pos < CAP) {
            slots[(size_t)d * CAP + pos] = (unsigned short)s;
        } else {                             // ~4 nodes expected (P(deg>32)~8e-5)
            int op = atomicAdd(ovf_cnt, 1);
            if (op < OVF_CAP)
                ovf[op] = ((unsigned int)d << 16) | (unsigned int)s;
        }
    }
}

// ---------- Kernel 3: gather both half-planes in one dispatch ----------
// First half of blocks -> plane 0 (cols 0..31), second half -> plane 1.
__global__ __launch_bounds__(256) void gather_pass_kernel(
    const unsigned short* __restrict__ slots, const int* __restrict__ cnt,
    const unsigned short* __restrict__ m0, const unsigned short* __restrict__ m1,
    const int* __restrict__ ovf_cnt, const unsigned int* __restrict__ ovf,
    float* __restrict__ out, int n_nodes, int gblocks) {
    const int plane = ((int)blockIdx.x >= gblocks) ? 1 : 0;
    const int blk = (int)blockIdx.x - plane * gblocks;
    const unsigned short* mplane = plane ? m1 : m0;
    const int col0 = plane * 32;

    const int lane = threadIdx.x & 63;
    const int l31 = lane & 31;
    const int wave = (blk * 256 + (int)threadIdx.x) >> 6;
    const int node = wave * 2 + ((lane >> 5) & 1);
    if (node >= n_nodes) return;

    const int c = cnt[node];
    const int cc = min(c, CAP);
    unsigned int idx = (unsigned int)slots[(size_t)node * CAP + l31];
    const int bsel = lane & 32;   // broadcast source base for this half-wave

    float acc = 0.0f;
    int k = 0;
    for (; k + 4 <= cc; k += 4) {
        unsigned int s0 = __shfl(idx, bsel + k + 0);
        unsigned int s1 = __shfl(idx, bsel + k + 1);
        unsigned int s2 = __shfl(idx, bsel + k + 2);
        unsigned int s3 = __shfl(idx, bsel + k + 3);
        float v0 = bf2f(mplane[(size_t)s0 * 32 + l31]);  // 64B row, L2-hot
        float v1 = bf2f(mplane[(size_t)s1 * 32 + l31]);
        float v2 = bf2f(mplane[(size_t)s2 * 32 + l31]);
        float v3 = bf2f(mplane[(size_t)s3 * 32 + l31]);
        acc += (v0 + v1) + (v2 + v3);
    }
    for (; k < cc; ++k) {
        unsigned int s = __shfl(idx, bsel + k);
        acc += bf2f(mplane[(size_t)s * 32 + l31]);
    }
    if (c > CAP) {                                   // rare: scan tiny ovf list
        int oc = min(*ovf_cnt, OVF_CAP);
        for (int i = 0; i < oc; ++i) {
            unsigned int e = ovf[i];
            if ((int)(e >> 16) == node)
                acc += bf2f(mplane[(size_t)(e & 0xFFFFu) * 32 + l31]);
        }
    }
    out[(size_t)node * D + col0 + l31] = acc;
}

// ---------- Fallback: atomic scatter (plane layout) ----------
__global__ __launch_bounds__(256) void edge_scatter_kernel(
    const int* __restrict__ src, const int* __restrict__ dst,
    const unsigned short* __restrict__ m0, const unsigned short* __restrict__ m1,
    float* __restrict__ out, int n_edges) {
    long long t = (long long)blockIdx.x * blockDim.x + threadIdx.x;
    int e = (int)(t >> 4);
    if (e >= n_edges) return;
    int c = (int)(t & 15) << 2;
    int s = src[e];
    int d = dst[e];
    const unsigned short* mp = (c < 32) ? m0 : m1;
    const ushort4 v = *(const ushort4*)(mp + (size_t)s * 32 + (c & 31));
    float* o = out + (size_t)d * D + c;
    atomicAdd(o + 0, bf2f(v.x));
    atomicAdd(o + 1, bf2f(v.y));
    atomicAdd(o + 2, bf2f(v.z));
    atomicAdd(o + 3, bf2f(v.w));
}

static inline size_t align_up(size_t v, size_t a) { return (v + a - 1) & ~(a - 1); }

extern "C" void kernel_launch(void* const* d_in, const int* in_sizes, int n_in,
                              void* d_out, int out_size, void* d_ws, size_t ws_size,
                              hipStream_t stream) {
    const float* x = (const float*)d_in[0];
    const int* edge_index = (const int*)d_in[1];   // int32 per harness contract
    const float* W = (const float*)d_in[2];
    const float* b = (const float*)d_in[3];
    float* out = (float*)d_out;

    const int n_nodes = in_sizes[0] / D;        // 50000
    const int n_edges = in_sizes[1] / 2;        // 800000
    const int* src = edge_index;                // row 0 (j, gather)
    const int* dst = edge_index + n_edges;      // row 1 (i, scatter)

    // Workspace layout (~10 MB total)
    size_t off = 0;
    unsigned short* m0 = (unsigned short*)((char*)d_ws + off);
    off = align_up(off + (size_t)n_nodes * 32 * sizeof(unsigned short), 256);
    unsigned short* m1 = (unsigned short*)((char*)d_ws + off);
    off = align_up(off + (size_t)n_nodes * 32 * sizeof(unsigned short), 256);
    int* cnt = (int*)((char*)d_ws + off);
    off = align_up(off + (size_t)n_nodes * sizeof(int), 256);
    unsigned short* slots = (unsigned short*)((char*)d_ws + off);
    off = align_up(off + (size_t)n_nodes * CAP * sizeof(unsigned short), 256);
    int* ovf_cnt = (int*)((char*)d_ws + off);
    off = align_up(off + sizeof(int), 256);
    unsigned int* ovf = (unsigned int*)((char*)d_ws + off);
    off = align_up(off + (size_t)OVF_CAP * sizeof(unsigned int), 256);
    const size_t needed = off;

    // Node MLP (+ fused cnt/ovf zeroing): 512 blocks -> 8 waves/CU
    node_mlp_kernel<<<512, 256, 0, stream>>>(x, W, b, m0, m1, cnt, ovf_cnt, n_nodes);

    if (ws_size >= needed && n_nodes <= 65536) {
        const int blocks_per_shard = 128;           // 1024 blocks total
        append_kernel<<<blocks_per_shard * NSHARD, 256, 0, stream>>>(
            src, dst, cnt, slots, ovf_cnt, ovf, n_edges, blocks_per_shard);
        const int gblocks = (n_nodes + 7) / 8;      // 8 nodes per block per plane
        gather_pass_kernel<<<gblocks * 2, 256, 0, stream>>>(
            slots, cnt, m0, m1, ovf_cnt, ovf, out, n_nodes, gblocks);
    } else {
        hipMemsetAsync(d_out, 0, (size_t)out_size * sizeof(float), stream);
        long long total_threads = (long long)n_edges * 16;
        int scat_blocks = (int)((total_threads + 255) / 256);
        edge_scatter_kernel<<<scat_blocks, 256, 0, stream>>>(src, dst, m0, m1,
                                                             out, n_edges);
    }
}